// Round 1
// baseline (6088.359 us; speedup 1.0000x reference)
//
#include <hip/hip_runtime.h>
#include <hip/hip_fp16.h>

#define BATCH 32
#define SEQ   1024
#define DIM   512

typedef _Float16 f16x2 __attribute__((ext_vector_type(2)));
typedef _Float16 f16x8 __attribute__((ext_vector_type(8)));
typedef float    f32x4 __attribute__((ext_vector_type(4)));

union U4H8 { uint4 u; f16x8 h8; };

static __device__ __forceinline__ f16x2 as_f16x2(unsigned int v) {
    union { unsigned int u; f16x2 h; } x; x.u = v; return x.h;
}

static __device__ __forceinline__ float fdot2(unsigned int a, unsigned int b, float c) {
    return __builtin_amdgcn_fdot2(as_f16x2(a), as_f16x2(b), c, false);
}

static __device__ __forceinline__ float tanh_fast(float x) {
    // 1 - 2/(e^{2x}+1): monotone, saturates correctly at +/-1 (no inf/inf NaN)
    float e = __expf(2.0f * x);
    return 1.0f - 2.0f / (e + 1.0f);
}

// ---------------------------------------------------------------------------
// Kernel 0: pack weights to fp16 in MFMA-/dot2-friendly layouts.
//  WpXh (for MFMA B-frags): half[((k>>5)*512 + n)*32 + ((k>>3)&3)*8 + (k&7)]
//    -> one uint4 per (k-block-of-32, col, lane-quad) = B fragment, coalesced.
//  WtHh (for dot2 streaming): half[((k>>3)*512 + e)*8 + (k&7)]
//    -> one uint4 per (k-group-of-8, col): 4 half2 along K.
// ---------------------------------------------------------------------------
__global__ void pack_weights(const float* __restrict__ Wxh,
                             const float* __restrict__ Whh,
                             __half* __restrict__ WpXh,
                             __half* __restrict__ WtHh) {
    int id = blockIdx.x * blockDim.x + threadIdx.x;   // 0 .. 262143
    int n = id & 511;
    int k = id >> 9;
    float wx = Wxh[k * 512 + n];
    float wh = Whh[k * 512 + n];
    WpXh[((k >> 5) * 512 + n) * 32 + ((k >> 3) & 3) * 8 + (k & 7)] = __float2half(wx);
    WtHh[((k >> 3) * 512 + n) * 8 + (k & 7)] = __float2half(wh);
}

// ---------------------------------------------------------------------------
// Kernel 1: xw = x @ W_xh + b, fp16 MFMA (16x16x32), fp32 out into d_out.
// Block = 256 threads = 4 waves; tile 64(M) x 64(N); wave w does rows [16w,16w+16).
// No LDS: A-frags loaded fp32->cvt from global; B-frags direct (pre-packed).
// A layout: A[m = lane&15][k = (lane>>4)*8 + j]; C: col=lane&15, row=(lane>>4)*4+r.
// ---------------------------------------------------------------------------
__global__ __launch_bounds__(256) void gemm_xw(const float* __restrict__ X,
                                               const __half* __restrict__ Wp,
                                               const float* __restrict__ bias,
                                               float* __restrict__ out) {
    const int nb   = blockIdx.x;        // 0..7
    const int mb   = blockIdx.y;        // 0..511
    const int lane = threadIdx.x & 63;
    const int wave = threadIdx.x >> 6;  // 0..3
    const int q    = lane >> 4;         // 0..3
    const int r16  = lane & 15;
    const int row  = mb * 64 + wave * 16 + r16;

    const float4* Xf4  = (const float4*)X;
    const uint4*  WpU4 = (const uint4*)Wp;

    f32x4 acc[4];
    #pragma unroll
    for (int nt = 0; nt < 4; ++nt) acc[nt] = (f32x4){0.f, 0.f, 0.f, 0.f};

    #pragma unroll 4
    for (int kb = 0; kb < 16; ++kb) {
        float4 a0 = Xf4[row * 128 + kb * 8 + q * 2];
        float4 a1 = Xf4[row * 128 + kb * 8 + q * 2 + 1];
        f16x8 af;
        af[0] = (_Float16)a0.x; af[1] = (_Float16)a0.y;
        af[2] = (_Float16)a0.z; af[3] = (_Float16)a0.w;
        af[4] = (_Float16)a1.x; af[5] = (_Float16)a1.y;
        af[6] = (_Float16)a1.z; af[7] = (_Float16)a1.w;
        #pragma unroll
        for (int nt = 0; nt < 4; ++nt) {
            int col = nb * 64 + nt * 16 + r16;
            U4H8 bf; bf.u = WpU4[(kb * 512 + col) * 4 + q];
            acc[nt] = __builtin_amdgcn_mfma_f32_16x16x32_f16(af, bf.h8, acc[nt], 0, 0, 0);
        }
    }

    const int rbase = mb * 64 + wave * 16 + q * 4;
    #pragma unroll
    for (int nt = 0; nt < 4; ++nt) {
        int col = nb * 64 + nt * 16 + r16;
        float bv = bias[col];
        #pragma unroll
        for (int rr = 0; rr < 4; ++rr) {
            out[(size_t)(rbase + rr) * 512 + col] = acc[nt][rr] + bv;
        }
    }
}

// ---------------------------------------------------------------------------
// Kernel 2: the recurrence. One block per batch element (communication-free).
// 256 threads; thread owns cols e and e+256. W_hh fp16: K-groups 0..23 resident
// in VGPRs (2x24 uint4 = 192 regs), groups 24..63 streamed from L2 each step.
// h (512 x fp16) double-buffered in LDS, read as wave-uniform ds_read_b128
// broadcasts. xw for step t+1 prefetched during step t to hide HBM latency.
// v_dot2_f32_f16: 256 MAC/cyc/CU -> ~1024 cyc/step floor.
// ---------------------------------------------------------------------------
__global__ __launch_bounds__(256, 1) void rnn_rec(const __half* __restrict__ Wt,
                                                  float* out) {
    const int b   = blockIdx.x;
    const int tid = threadIdx.x;
    const int e0  = tid;
    const int e1  = tid + 256;
    const uint4* WtU4 = (const uint4*)Wt;

    __shared__ uint4 lh[2][64];   // 2 x 512 halves, h double buffer
    if (tid < 128) ((uint4*)lh)[tid] = make_uint4(0u, 0u, 0u, 0u);
    __syncthreads();

    // Resident W: K rows 0..191 for both columns.
    uint4 RW0[24], RW1[24];
    #pragma unroll
    for (int g = 0; g < 24; ++g) {
        RW0[g] = WtU4[g * 512 + e0];
        RW1[g] = WtU4[g * 512 + e1];
    }

    float* orow = out + (size_t)b * SEQ * DIM;
    float nxw0 = orow[e0];
    float nxw1 = orow[e1];
    float h0 = 0.f, h1 = 0.f;

    for (int t = 0; t < SEQ; ++t) {
        const int cur = t & 1;
        const int nxt = cur ^ 1;
        float xw0 = nxw0, xw1 = nxw1;
        // Prefetch next step's xw (this thread owns those addresses; nobody
        // else writes them, so reading early across the barrier is safe).
        if (t + 1 < SEQ) {
            nxw0 = orow[DIM + e0];
            nxw1 = orow[DIM + e1];
        }

        const uint4* H = lh[cur];
        float a0 = 0.f, a1 = 0.f, a2 = 0.f, a3 = 0.f;
        float c0 = 0.f, c1 = 0.f, c2 = 0.f, c3 = 0.f;

        #pragma unroll
        for (int g = 0; g < 24; ++g) {
            uint4 hv = H[g];
            a0 = fdot2(RW0[g].x, hv.x, a0);
            a1 = fdot2(RW0[g].y, hv.y, a1);
            a2 = fdot2(RW0[g].z, hv.z, a2);
            a3 = fdot2(RW0[g].w, hv.w, a3);
            c0 = fdot2(RW1[g].x, hv.x, c0);
            c1 = fdot2(RW1[g].y, hv.y, c1);
            c2 = fdot2(RW1[g].z, hv.z, c2);
            c3 = fdot2(RW1[g].w, hv.w, c3);
        }
        #pragma unroll 8
        for (int g = 24; g < 64; ++g) {
            uint4 hv = H[g];
            uint4 w0 = WtU4[g * 512 + e0];
            uint4 w1 = WtU4[g * 512 + e1];
            a0 = fdot2(w0.x, hv.x, a0);
            a1 = fdot2(w0.y, hv.y, a1);
            a2 = fdot2(w0.z, hv.z, a2);
            a3 = fdot2(w0.w, hv.w, a3);
            c0 = fdot2(w1.x, hv.x, c0);
            c1 = fdot2(w1.y, hv.y, c1);
            c2 = fdot2(w1.z, hv.z, c2);
            c3 = fdot2(w1.w, hv.w, c3);
        }

        float p0 = xw0 + ((a0 + a1) + (a2 + a3));
        float p1 = xw1 + ((c0 + c1) + (c2 + c3));
        h0 = tanh_fast(p0);
        h1 = tanh_fast(p1);

        orow[e0] = h0;
        orow[e1] = h1;
        __half* hn = (__half*)lh[nxt];
        hn[e0] = __float2half(h0);
        hn[e1] = __float2half(h1);
        __syncthreads();
        orow += DIM;
    }

    // h_final = h_{T-1}
    float* hf = out + (size_t)BATCH * SEQ * DIM + (size_t)b * DIM;
    hf[e0] = h0;
    hf[e1] = h1;
}

extern "C" void kernel_launch(void* const* d_in, const int* in_sizes, int n_in,
                              void* d_out, int out_size, void* d_ws, size_t ws_size,
                              hipStream_t stream) {
    const float* X    = (const float*)d_in[0];   // [32,1024,512] fp32
    const float* Wxh  = (const float*)d_in[1];   // [512,512] fp32
    const float* Whh  = (const float*)d_in[2];   // [512,512] fp32
    const float* bias = (const float*)d_in[3];   // [512] fp32
    float* out = (float*)d_out;                  // [32*1024*512 + 32*512] fp32

    __half* WpXh = (__half*)d_ws;                          // 512 KB
    __half* WtHh = (__half*)((char*)d_ws + (512u << 10));  // 512 KB

    pack_weights<<<512, 512, 0, stream>>>(Wxh, Whh, WpXh, WtHh);
    gemm_xw<<<dim3(8, 512), 256, 0, stream>>>(X, WpXh, bias, out);
    rnn_rec<<<BATCH, 256, 0, stream>>>(WtHh, out);
}

// Round 3
// 3017.114 us; speedup vs baseline: 2.0179x; 2.0179x over previous
//
#include <hip/hip_runtime.h>
#include <hip/hip_fp16.h>

#define BATCH 32
#define SEQ   1024
#define DIM   512

typedef _Float16 f16x2 __attribute__((ext_vector_type(2)));
typedef _Float16 f16x8 __attribute__((ext_vector_type(8)));
typedef float    f32x4 __attribute__((ext_vector_type(4)));

union U4H8 { uint4 u; f16x8 h8; };

static __device__ __forceinline__ f16x2 as_f16x2(unsigned int v) {
    union { unsigned int u; f16x2 h; } x; x.u = v; return x.h;
}

static __device__ __forceinline__ float fdot2(unsigned int a, unsigned int b, float c) {
    return __builtin_amdgcn_fdot2(as_f16x2(a), as_f16x2(b), c, false);
}

static __device__ __forceinline__ unsigned pack2h(float a, float b) {
    auto p = __builtin_amdgcn_cvt_pkrtz(a, b);   // __fp16 ext_vector(2)
    union { decltype(p) h; unsigned u; } x; x.h = p; return x.u;
}

static __device__ __forceinline__ float tanh_fast(float x) {
    float e = __expf(2.0f * x);
    return 1.0f - 2.0f / (e + 1.0f);
}

// ---------------------------------------------------------------------------
// Pack W_xh into MFMA B-fragment layout (fp16) for gemm_xw.
// ---------------------------------------------------------------------------
__global__ void pack_wxh(const float* __restrict__ Wxh, __half* __restrict__ WpXh) {
    int id = blockIdx.x * blockDim.x + threadIdx.x;   // 0 .. 262143
    int n = id & 511;
    int k = id >> 9;
    WpXh[((k >> 5) * 512 + n) * 32 + ((k >> 3) & 3) * 8 + (k & 7)] = __float2half(Wxh[k * 512 + n]);
}

// ---------------------------------------------------------------------------
// Pack W_hh (fp16, k-pairs packed into words) for the recurrence.
//  word(w, c) = {Whh[2w][c], Whh[2w+1][c]} as half2 in a uint.
//  Wres[w*256 + t] = uint2{ word(w,2t), word(w,2t+1) }          for w in [0,192)
//  Wstr[(p*256 + t)] = uint4{ word(192+2p,2t), word(192+2p,2t+1),
//                             word(193+2p,2t), word(193+2p,2t+1) } p in [0,32)
// ---------------------------------------------------------------------------
__global__ void pack_whh(const float* __restrict__ Whh,
                         uint2* __restrict__ Wres,
                         uint2* __restrict__ Wstr2) {
    int id = blockIdx.x * blockDim.x + threadIdx.x;   // 0 .. 65535
    int w = id >> 8;          // 0..255
    int t = id & 255;
    int c0 = 2 * t;
    unsigned w0 = pack2h(Whh[(2 * w) * 512 + c0],     Whh[(2 * w + 1) * 512 + c0]);
    unsigned w1 = pack2h(Whh[(2 * w) * 512 + c0 + 1], Whh[(2 * w + 1) * 512 + c0 + 1]);
    if (w < 192) {
        Wres[w * 256 + t] = make_uint2(w0, w1);
    } else {
        int p = (w - 192) >> 1;
        Wstr2[(p * 256 + t) * 2 + (w & 1)] = make_uint2(w0, w1);
    }
}

// ---------------------------------------------------------------------------
// Kernel 1: xw = x @ W_xh + b (fp16 MFMA 16x16x32, fp32 out).
// ---------------------------------------------------------------------------
__global__ __launch_bounds__(256) void gemm_xw(const float* __restrict__ X,
                                               const __half* __restrict__ Wp,
                                               const float* __restrict__ bias,
                                               float* __restrict__ out) {
    const int nb   = blockIdx.x;        // 0..7
    const int mb   = blockIdx.y;        // 0..511
    const int lane = threadIdx.x & 63;
    const int wave = threadIdx.x >> 6;  // 0..3
    const int q    = lane >> 4;         // 0..3
    const int r16  = lane & 15;
    const int row  = mb * 64 + wave * 16 + r16;

    const float4* Xf4  = (const float4*)X;
    const uint4*  WpU4 = (const uint4*)Wp;

    f32x4 acc[4];
    #pragma unroll
    for (int nt = 0; nt < 4; ++nt) acc[nt] = (f32x4){0.f, 0.f, 0.f, 0.f};

    #pragma unroll 4
    for (int kb = 0; kb < 16; ++kb) {
        float4 a0 = Xf4[row * 128 + kb * 8 + q * 2];
        float4 a1 = Xf4[row * 128 + kb * 8 + q * 2 + 1];
        f16x8 af;
        af[0] = (_Float16)a0.x; af[1] = (_Float16)a0.y;
        af[2] = (_Float16)a0.z; af[3] = (_Float16)a0.w;
        af[4] = (_Float16)a1.x; af[5] = (_Float16)a1.y;
        af[6] = (_Float16)a1.z; af[7] = (_Float16)a1.w;
        #pragma unroll
        for (int nt = 0; nt < 4; ++nt) {
            int col = nb * 64 + nt * 16 + r16;
            U4H8 bf; bf.u = WpU4[(kb * 512 + col) * 4 + q];
            acc[nt] = __builtin_amdgcn_mfma_f32_16x16x32_f16(af, bf.h8, acc[nt], 0, 0, 0);
        }
    }

    const int rbase = mb * 64 + wave * 16 + q * 4;
    #pragma unroll
    for (int nt = 0; nt < 4; ++nt) {
        int col = nb * 64 + nt * 16 + r16;
        float bv = bias[col];
        #pragma unroll
        for (int rr = 0; rr < 4; ++rr) {
            out[(size_t)(rbase + rr) * 512 + col] = acc[nt][rr] + bv;
        }
    }
}

// ---------------------------------------------------------------------------
// Kernel 2: recurrence. One block (256 thr, 4 waves, 1 wave/SIMD) per batch.
// Thread owns cols 2t, 2t+1. W_hh: k=0..383 VGPR-resident (384 regs, pinned
// with asm), k=384..511 in LDS (128 KB, conflict-free per-lane b128 reads).
// h distribution: ONE ds_read_b128 per wave (whole 1 KB h vector across 64
// lanes) + v_readlane -> SGPR -> scalar src of v_dot2_f32_f16.
// ---------------------------------------------------------------------------
#define H_WORD(w) __builtin_amdgcn_readlane((int)((((w) & 3) == 0) ? hva : (((w) & 3) == 1) ? hvb : (((w) & 3) == 2) ? hvc : hvd), (w) >> 2)

__global__ __launch_bounds__(256, 1) void rnn_rec(const uint2* __restrict__ Wres,
                                                  const uint4* __restrict__ Wstr,
                                                  float* __restrict__ out) {
    extern __shared__ char smem[];
    uint4*    Wl  = (uint4*)smem;                       // 32*256*16 = 128 KB
    unsigned* hb0 = (unsigned*)(smem + 131072);         // 1 KB
    unsigned* hb1 = hb0 + 256;                          // 1 KB

    const int b    = blockIdx.x;
    const int t    = threadIdx.x;
    const int lane = t & 63;

    // One-time: stage streamed W into LDS (coalesced, conflict-free).
    #pragma unroll 4
    for (int p = 0; p < 32; ++p) Wl[p * 256 + t] = Wstr[p * 256 + t];

    // Resident W: k-words 0..191 for this thread's two columns. Pin in VGPRs.
    unsigned Wr0[192], Wr1[192];
    #pragma unroll
    for (int w = 0; w < 192; ++w) {
        uint2 v = Wres[w * 256 + t];
        Wr0[w] = v.x; Wr1[w] = v.y;
        asm volatile("" : "+v"(Wr0[w]), "+v"(Wr1[w]));
    }

    float* orow = out + (size_t)b * SEQ * DIM;

    // t = 0: h = tanh(xw)
    float2 xw0 = ((const float2*)orow)[t];
    float h0 = tanh_fast(xw0.x);
    float h1 = tanh_fast(xw0.y);
    ((float2*)orow)[t] = make_float2(h0, h1);
    hb0[t] = pack2h(h0, h1);
    float2 xwc = ((const float2*)(orow + DIM))[t];   // xw for step 1
    __syncthreads();
    uint4 hv4 = ((const uint4*)hb0)[lane];
    unsigned hva = hv4.x, hvb = hv4.y, hvc = hv4.z, hvd = hv4.w;

    for (int step = 1; step < SEQ; ++step) {
        orow += DIM;
        float a0 = 0.f, a1 = 0.f, c0 = 0.f, c1 = 0.f;

        // Streamed part first: LDS reads independent of readlanes.
        #pragma unroll 8
        for (int p = 0; p < 32; ++p) {
            uint4 wv = Wl[p * 256 + t];
            unsigned hw0 = (unsigned)H_WORD(192 + 2 * p);
            unsigned hw1 = (unsigned)H_WORD(193 + 2 * p);
            a0 = fdot2(wv.x, hw0, a0);
            c0 = fdot2(wv.y, hw0, c0);
            a1 = fdot2(wv.z, hw1, a1);
            c1 = fdot2(wv.w, hw1, c1);
        }
        // Resident part (fully unrolled; constant lane/component indices).
        #pragma unroll
        for (int w = 0; w < 192; w += 2) {
            unsigned hw0 = (unsigned)H_WORD(w);
            unsigned hw1 = (unsigned)H_WORD(w + 1);
            a0 = fdot2(Wr0[w], hw0, a0);
            c0 = fdot2(Wr1[w], hw0, c0);
            a1 = fdot2(Wr0[w + 1], hw1, a1);
            c1 = fdot2(Wr1[w + 1], hw1, c1);
        }

        float h0n = tanh_fast(xwc.x + (a0 + a1));
        float h1n = tanh_fast(xwc.y + (c0 + c1));
        h0 = h0n; h1 = h1n;

        // Prefetch next xw (address stays in-bounds even at step 1023).
        xwc = ((const float2*)(orow + DIM))[t];

        ((float2*)orow)[t] = make_float2(h0, h1);
        unsigned* hbN = (step & 1) ? hb1 : hb0;
        hbN[t] = pack2h(h0, h1);
        __syncthreads();
        uint4 nh = ((const uint4*)((step & 1) ? hb1 : hb0))[lane];
        hva = nh.x; hvb = nh.y; hvc = nh.z; hvd = nh.w;
    }

    float* hf = out + (size_t)BATCH * SEQ * DIM + (size_t)b * DIM;
    ((float2*)hf)[t] = make_float2(h0, h1);
}

extern "C" void kernel_launch(void* const* d_in, const int* in_sizes, int n_in,
                              void* d_out, int out_size, void* d_ws, size_t ws_size,
                              hipStream_t stream) {
    const float* X    = (const float*)d_in[0];   // [32,1024,512] fp32
    const float* Wxh  = (const float*)d_in[1];   // [512,512] fp32
    const float* Whh  = (const float*)d_in[2];   // [512,512] fp32
    const float* bias = (const float*)d_in[3];   // [512] fp32
    float* out = (float*)d_out;

    __half* WpXh = (__half*)d_ws;                              // 512 KB
    uint2*  Wres = (uint2*)((char*)d_ws + (512u << 10));       // 384 KB
    uint4*  Wstr = (uint4*)((char*)d_ws + (896u << 10));       // 128 KB

    (void)hipFuncSetAttribute((const void*)rnn_rec,
                              hipFuncAttributeMaxDynamicSharedMemorySize, 133120);

    pack_wxh<<<512, 512, 0, stream>>>(Wxh, WpXh);
    pack_whh<<<256, 256, 0, stream>>>(Whh, Wres, (uint2*)Wstr);
    gemm_xw<<<dim3(8, 512), 256, 0, stream>>>(X, WpXh, bias, out);
    rnn_rec<<<BATCH, 256, 133120, stream>>>(Wres, Wstr, out);
}